// Round 11
// baseline (303.032 us; speedup 1.0000x reference)
//
#include <hip/hip_runtime.h>
#include <hip/hip_bf16.h>
#include <cstdint>
#include <cstddef>

using bf16 = __hip_bfloat16;
typedef __attribute__((ext_vector_type(8))) short short8;
typedef __attribute__((ext_vector_type(4))) float floatx4;

#define B_ 4
#define T_ 2048
#define C_ 1024
#define H_ 16
#define HS_ 64
#define BT_ (B_*T_)
#define N3C (3*C_)

#define MFMA16(a,b,c) __builtin_amdgcn_mfma_f32_16x16x32_bf16((a),(b),(c),0,0,0)

#if __has_builtin(__builtin_amdgcn_exp2f)
#define EXP2(x) __builtin_amdgcn_exp2f(x)
#else
#define EXP2(x) exp2f(x)
#endif

static __device__ __forceinline__ void gld16(const bf16* g, bf16* l) {
  __builtin_amdgcn_global_load_lds(
      (const __attribute__((address_space(1))) unsigned int*)g,
      (__attribute__((address_space(3))) unsigned int*)l, 16, 0, 0);
}

static __device__ __forceinline__ unsigned short f2bf_us(float x) {
  bf16 b = __float2bfloat16(x);
  return *(unsigned short*)&b;
}

// ---------------- fused prep: cast x + transpose-cast both weights ----------
__global__ __launch_bounds__(256)
void k_prep(const float* __restrict__ x, bf16* __restrict__ xb,
            const float* __restrict__ Wqkv, bf16* __restrict__ wqkvT,
            const float* __restrict__ Wproj, bf16* __restrict__ wprojT)
{
  const int bid = blockIdx.x, tid = threadIdx.x;
  __shared__ float tile[64][65];

  if (bid < 4096) {
    const int i = bid*256 + tid;
    const float4 v0 = ((const float4*)x)[2*i];
    const float4 v1 = ((const float4*)x)[2*i + 1];
    union { bf16 b[8]; uint4 u; } cvt;
    cvt.b[0] = __float2bfloat16(v0.x);
    cvt.b[1] = __float2bfloat16(v0.y);
    cvt.b[2] = __float2bfloat16(v0.z);
    cvt.b[3] = __float2bfloat16(v0.w);
    cvt.b[4] = __float2bfloat16(v1.x);
    cvt.b[5] = __float2bfloat16(v1.y);
    cvt.b[6] = __float2bfloat16(v1.z);
    cvt.b[7] = __float2bfloat16(v1.w);
    ((uint4*)xb)[i] = cvt.u;
    return;
  }

  const float* in; bf16* out; int N, n0, k0;
  if (bid < 4864) {
    const int j = bid - 4096;
    in = Wqkv; out = wqkvT; N = N3C;
    n0 = (j % 48) * 64; k0 = (j / 48) * 64;
  } else {
    const int j = bid - 4864;
    in = Wproj; out = wprojT; N = C_;
    n0 = (j % 16) * 64; k0 = (j / 16) * 64;
  }
  const int r = tid >> 6, c = tid & 63;
  #pragma unroll
  for (int j = 0; j < 16; ++j)
    tile[r + j*4][c] = in[(size_t)(k0 + r + j*4) * N + n0 + c];
  __syncthreads();
  #pragma unroll
  for (int j = 0; j < 16; ++j) {
    int rr = r + j*4;
    out[(size_t)(n0 + rr) * C_ + k0 + c] = __float2bfloat16(tile[c][rr]);
  }
}

// ---------------- QKV GEMM: 256x384, BK=32, 3-buf, 1-barrier/tile -----------
// R16 structure (proven): grid 256 = 1 block/CU tail-free; BN=384 as {Q,K,V}
// 128-col groups; 8 waves 2Mx4N acc[8][6]; verified 0-conflict swizzle;
// one counted vmcnt(5) + one barrier per K-tile, free-scheduling window.
__global__ __launch_bounds__(512, 1)
void k_gemmqkv(const bf16* __restrict__ A, const bf16* __restrict__ Bt,
               bf16* __restrict__ Qb, bf16* __restrict__ Kb, bf16* __restrict__ Vt)
{
  __shared__ __align__(16) char smem[122880];
  bf16* const sA = (bf16*)smem;                 // [3][8192]  256 rows x 32
  bf16* const sB = (bf16*)(smem + 49152);       // [3][12288] 384 rows x 32

  const int tid  = threadIdx.x;
  const int lane = tid & 63, wave = tid >> 6;
  const int quad = lane >> 4, l16 = lane & 15;
  const int wm = wave >> 2, wn = wave & 3;      // 2M x 4N

  const int g = blockIdx.x;                     // 256 blocks
  const int xcd = g & 7;
  const int local = g >> 3;                     // 0..31
  const int nb = local & 7;
  const int mb = (local >> 3) * 8 + xcd;        // 0..31
  const int m0 = mb * 256;
  const int n0q = nb * 128;

  const int ra = tid >> 2;
  const int gc = (tid & 3) ^ ((ra >> 1) & 3);
  const bf16* aptr = A  + (size_t)(m0 + ra) * C_ + gc*8;
  const bf16* bp0  = Bt + (size_t)(n0q + ra) * C_ + gc*8;          // Q group
  const bf16* bp1  = Bt + (size_t)(1024 + n0q + ra) * C_ + gc*8;   // K group
  const bf16* bp2  = Bt + (size_t)(2048 + n0q + ra) * C_ + gc*8;   // V group

  floatx4 acc[8][6] = {};
  const int swz = (l16 >> 1) & 3;
  const int aoff = (wm*128 + l16)*32 + (quad ^ swz)*8;
  const int boff = (wn*96  + l16)*32 + (quad ^ swz)*8;

#define STAGE_A(t,s) { bf16* d = sA + (s)*8192;                     \
    gld16(aptr + (t)*32,                  d + tid*8);               \
    gld16(aptr + (size_t)128*C_ + (t)*32, d + 4096 + tid*8); }
#define STAGE_B(t,s) { bf16* d = sB + (s)*12288;                    \
    gld16(bp0 + (t)*32, d + tid*8);                                 \
    gld16(bp1 + (t)*32, d + 4096 + tid*8);                         \
    gld16(bp2 + (t)*32, d + 8192 + tid*8); }

  // prologue: tiles 0,1 staged (10 loads in flight; 5 per tile per wave)
  STAGE_A(0,0); STAGE_B(0,0);
  STAGE_A(1,1); STAGE_B(1,1);

  int cs = 0;                                   // i % 3
  #pragma unroll 1
  for (int i = 0; i < 32; ++i) {
    const int s2 = (cs >= 1) ? cs - 1 : 2;      // (i+2) % 3
    if (i < 31) asm volatile("s_waitcnt vmcnt(5)" ::: "memory");  // tile i done
    else        asm volatile("s_waitcnt vmcnt(0)" ::: "memory");
    __builtin_amdgcn_sched_barrier(0);          // tile boundary: no reg-op motion
    asm volatile("s_barrier" ::: "memory");
    if (i < 30) { STAGE_A(i+2, s2); STAGE_B(i+2, s2); }
    const bf16* sa = sA + cs*8192;
    const bf16* sb = sB + cs*12288;
    short8 bq[6], af[4];
    #pragma unroll
    for (int j = 0; j < 6; ++j)    bq[j]  = *(const short8*)&sb[boff + j*512];
    #pragma unroll
    for (int ii = 0; ii < 4; ++ii) af[ii] = *(const short8*)&sa[aoff + ii*512];
    __builtin_amdgcn_s_setprio(1);
    #pragma unroll
    for (int ii = 0; ii < 4; ++ii)
      #pragma unroll
      for (int j = 0; j < 6; ++j)
        acc[ii][j] = MFMA16(af[ii], bq[j], acc[ii][j]);
    __builtin_amdgcn_s_setprio(0);
    #pragma unroll
    for (int ii = 0; ii < 4; ++ii) af[ii] = *(const short8*)&sa[aoff + (4+ii)*512];
    __builtin_amdgcn_s_setprio(1);
    #pragma unroll
    for (int ii = 0; ii < 4; ++ii)
      #pragma unroll
      for (int j = 0; j < 6; ++j)
        acc[4+ii][j] = MFMA16(af[ii], bq[j], acc[4+ii][j]);
    __builtin_amdgcn_s_setprio(0);
    cs = (cs == 2) ? 0 : cs + 1;
  }
#undef STAGE_A
#undef STAGE_B

  // ---- Q/K scatter (local cols 0-255) ----
  #pragma unroll
  for (int ii = 0; ii < 8; ++ii) {
    const int rowb = m0 + wm*128 + ii*16 + quad*4;
    #pragma unroll
    for (int j = 0; j < 6; ++j) {
      const int L = wn*96 + j*16 + l16;          // 16-aligned span: uniform side
      if (L < 256) {
        const int gcol = (L < 128) ? (n0q + L) : (1024 + n0q + L - 128);
        const int h = (gcol >> 6) & 15, d = gcol & 63;
        #pragma unroll
        for (int r = 0; r < 4; ++r) {
          const int rr = rowb + r;
          const int b = rr >> 11, t = rr & 2047;
          const size_t addr = (((size_t)(b*H_ + h) * T_ + t) << 6) + d;
          if (L < 128) Qb[addr] = __float2bfloat16(acc[ii][j][r] * 0.18033688f);
          else         Kb[addr] = __float2bfloat16(acc[ii][j][r]);
        }
      }
    }
  }

  // ---- V (local cols 256-383): LDS transpose -> key-permuted Vt ----
  __syncthreads();                               // all waves done with sA/sB
  unsigned short* epi = (unsigned short*)smem;   // [128 cc][258 tl-pad]
  #pragma unroll
  for (int ii = 0; ii < 8; ++ii) {
    const int tl = wm*128 + ii*16 + quad*4;
    #pragma unroll
    for (int j = 0; j < 6; ++j) {
      const int L = wn*96 + j*16 + l16;
      if (L >= 256) {
        const int ccl = L - 256;                 // 0..127
        #pragma unroll
        for (int r = 0; r < 4; ++r)
          epi[ccl*258 + tl + r] = f2bf_us(acc[ii][j][r]);
      }
    }
  }
  __syncthreads();
  const int b  = m0 >> 11;
  const int t0 = m0 & 2047;
  #pragma unroll
  for (int it = 0; it < 32; ++it) {
    const int id = it*512 + tid;                 // 16384 dword-pairs
    const int tp = id & 31;
    const int rest = id >> 5;                    // 0..511
    const int tl64 = (rest & 3) * 64;            // 64-token group of 256 rows
    const int ccl = rest >> 2;                   // 0..127
    const int k0p = tp + (tp & 16);              // keys (k0p,k0p+16)->(2tp,2tp+1)
    const unsigned lo = epi[ccl*258 + tl64 + k0p];
    const unsigned hi = epi[ccl*258 + tl64 + k0p + 16];
    const int h = nb*2 + (ccl >> 6), d = ccl & 63;
    unsigned* row = (unsigned*)(Vt + ((size_t)(b*H_ + h) * HS_ + d) * T_);
    row[(t0 >> 1) + tl64/2 + tp] = lo | (hi << 16);
  }
}

// ---------------- proj GEMM: 128x128, BK=32, 4-deep counted-vmcnt -----------
template<int NB>
__global__ __launch_bounds__(256, 2)
void k_proj(const bf16* __restrict__ A, const bf16* __restrict__ Bt,
            int N, int K, float* __restrict__ Out, const float* __restrict__ bias)
{
  __shared__ __align__(16) char smem[65536];
  bf16* const sA = (bf16*)smem;               // [4][4096]  128 rows x 32
  bf16* const sB = (bf16*)(smem + 32768);     // [4][4096]

  const int tid  = threadIdx.x;
  const int lane = tid & 63, wave = tid >> 6;
  const int quad = lane >> 4, l16 = lane & 15;
  const int wm = wave >> 1, wn = wave & 1;

  const int g = blockIdx.x;
  const int xcd = g & 7;
  const int local = g >> 3;
  const int nb = local % NB;
  const int mb = (local / NB) * 8 + xcd;
  const int m0 = mb * 128, n0 = nb * 128;

  const int ra = tid >> 2;
  const int gc = (tid & 3) ^ ((ra >> 1) & 3);
  const bf16* aptr = A  + (size_t)(m0 + ra) * K + gc*8;
  const bf16* bptr = Bt + (size_t)(n0 + ra) * K + gc*8;
  const size_t rj = (size_t)64 * K;

  const int KT = K >> 5;                      // 32 K-tiles
  floatx4 acc[4][4] = {};
  const int swz = (l16 >> 1) & 3;
  const int aoff = (wm*64 + l16)*32 + (quad ^ swz)*8;
  const int boff = (wn*64 + l16)*32 + (quad ^ swz)*8;

  #pragma unroll
  for (int t = 0; t < 3; ++t) {
    bf16* sa = sA + t*4096; bf16* sb = sB + t*4096;
    gld16(aptr + t*32,      sa + tid*8);
    gld16(aptr + rj + t*32, sa + 2048 + tid*8);
    gld16(bptr + t*32,      sb + tid*8);
    gld16(bptr + rj + t*32, sb + 2048 + tid*8);
  }

  #pragma unroll 1
  for (int i = 0; i < KT; ++i) {
    if (i < KT-2)       asm volatile("s_waitcnt vmcnt(8)" ::: "memory");
    else if (i == KT-2) asm volatile("s_waitcnt vmcnt(4)" ::: "memory");
    else                asm volatile("s_waitcnt vmcnt(0)" ::: "memory");
    asm volatile("s_barrier" ::: "memory");
    if (i < KT-3) {
      const int t = i + 3;
      bf16* sa = sA + (t & 3)*4096; bf16* sb = sB + (t & 3)*4096;
      gld16(aptr + t*32,      sa + tid*8);
      gld16(aptr + rj + t*32, sa + 2048 + tid*8);
      gld16(bptr + t*32,      sb + tid*8);
      gld16(bptr + rj + t*32, sb + 2048 + tid*8);
    }
    const bf16* sa = sA + (i & 3)*4096;
    const bf16* sb = sB + (i & 3)*4096;
    short8 af[4], bfm[4];
    #pragma unroll
    for (int ii = 0; ii < 4; ++ii) af[ii]  = *(const short8*)&sa[aoff + ii*512];
    #pragma unroll
    for (int j = 0; j < 4; ++j)    bfm[j]  = *(const short8*)&sb[boff + j*512];
    __builtin_amdgcn_s_setprio(1);
    #pragma unroll
    for (int ii = 0; ii < 4; ++ii)
      #pragma unroll
      for (int j = 0; j < 4; ++j)
        acc[ii][j] = MFMA16(af[ii], bfm[j], acc[ii][j]);
    __builtin_amdgcn_s_setprio(0);
  }

  #pragma unroll
  for (int i = 0; i < 4; ++i) {
    const int rowb = m0 + wm*64 + i*16 + quad*4;
    #pragma unroll
    for (int j = 0; j < 4; ++j) {
      const int col = n0 + wn*64 + j*16 + l16;
      #pragma unroll
      for (int r = 0; r < 4; ++r)
        Out[(size_t)(rowb + r) * N + col] = acc[i][j][r] + bias[col];
    }
  }
}

// ---------------- flash attention (causal, L2-direct K/V reads) -------------
// R20: delete the K/V LDS staging. Per-bh K+V = 512KB; the XCD-pinned
// mapping gives each XCD exactly 8 bh = 4MB = its L2, written there by
// k_gemmqkv. Fragment addresses after unwinding the staging XOR are plain
// per-lane 16B global loads: K row (tk0+nt*16+l16) at chunk (ss*4+quad);
// Vt row (nd*16+l16) at tk0 + chunk (ss*4+quad). This removes both K/V LDS
// buffers, all gld16 staging, the double-buffer, and EVERY __syncthreads -
// waves run free (per-wave break on the causal frontier), and the LDS pipe
// (formerly the serializer) carries only the per-wave P roundtrip.
// LDS 49KB -> 16KB; VGPR ~116 <= 128 -> 4 blocks/CU (16 waves/CU).
// Numerics bit-identical (same operands, same MFMA order).
__global__ __launch_bounds__(256, 3)
void k_attn(const bf16* __restrict__ Q, const bf16* __restrict__ K,
            const bf16* __restrict__ Vt, bf16* __restrict__ att)
{
  __shared__ bf16 pbuf[4][32*64];   // per-wave [q][(pc+q)&7 rotation], no sync

  const int tid  = threadIdx.x;
  const int lane = tid & 63, wave = tid >> 6;
  const int quad = lane >> 4, l16 = lane & 15;

  const int g  = blockIdx.x;              // 1024 blocks
  const int bh = (g & 7) * 8 + ((g >> 3) & 7);  // 16 blocks of a bh share XCD g&7
  const int qt = 15 - (g >> 6);           // q-tile index; heavy (qt=15) first
  const int b = bh >> 4, h = bh & 15;

  const bf16* Qp = Q  + (size_t)bh * T_ * HS_;
  const bf16* Kp = K  + (size_t)bh * T_ * HS_;
  const bf16* Vp = Vt + (size_t)bh * HS_ * T_;

  const int qbase = qt*128 + wave*32;
  const int ntk = 2*qt + 2;               // block-level key-tile bound

  short8 qf[2][2];
  #pragma unroll
  for (int mt = 0; mt < 2; ++mt)
    #pragma unroll
    for (int ss = 0; ss < 2; ++ss)
      qf[mt][ss] = *(const short8*)(Qp + (size_t)(qbase + mt*16 + l16) * HS_ + ss*32 + quad*8);

  floatx4 o[2][4] = {};
  float lrow[2][4] = {};

  // per-lane K/V fragment bases (chunk ss*4+quad of each row)
  const bf16* kbase = Kp + (size_t)l16 * HS_ + quad*8;
  const bf16* vbase = Vp + (size_t)l16 * T_  + quad*8;

  bf16* pw = pbuf[wave];
  unsigned int* pw32 = (unsigned int*)pw;
  const int c0 = l16 >> 2;
  const int dwl = l16 & 3;

  #pragma unroll 1
  for (int tk = 0; tk < ntk; ++tk) {
    const int tk0 = tk * 64;
    if (tk0 > qbase + 31) break;          // causal frontier (tiles ascend)

    // S = Q K^T (log2 domain; Q pre-scaled); K fragments straight from L2
    floatx4 s[2][4] = {};
    __builtin_amdgcn_s_setprio(1);
    #pragma unroll
    for (int nt = 0; nt < 4; ++nt) {
      const bf16* kr = kbase + (size_t)(tk0 + nt*16) * HS_;
      #pragma unroll
      for (int ss = 0; ss < 2; ++ss) {
        short8 kf = *(const short8*)(kr + ss*32);
        s[0][nt] = MFMA16(qf[0][ss], kf, s[0][nt]);
        s[1][nt] = MFMA16(qf[1][ss], kf, s[1][nt]);
      }
    }
    __builtin_amdgcn_s_setprio(0);

    // causal mask on diagonal band (exp2(-1e30) == 0)
    if (tk0 + 63 > qbase) {
      #pragma unroll
      for (int mt = 0; mt < 2; ++mt)
        #pragma unroll
        for (int nt = 0; nt < 4; ++nt) {
          const int key = tk0 + nt*16 + l16;
          #pragma unroll
          for (int r = 0; r < 4; ++r) {
            const int qr = qbase + mt*16 + quad*4 + r;
            if (key > qr) s[mt][nt][r] = -1e30f;
          }
        }
    }

    // un-shifted softmax: P = exp2(s), l += sum(P);
    // pack P pairs (key, key+16) -> dword, matching the Vt pair layout.
    #pragma unroll
    for (int mt = 0; mt < 2; ++mt) {
      #pragma unroll
      for (int r = 0; r < 4; ++r) {
        const float p0 = EXP2(s[mt][0][r]), p1 = EXP2(s[mt][1][r]);
        const float p2 = EXP2(s[mt][2][r]), p3 = EXP2(s[mt][3][r]);
        lrow[mt][r] += (p0 + p1) + (p2 + p3);
        const int q = mt*16 + quad*4 + r;
        const unsigned w0 = __builtin_amdgcn_perm(__float_as_uint(p1), __float_as_uint(p0), 0x07060302u);
        const unsigned w1 = __builtin_amdgcn_perm(__float_as_uint(p3), __float_as_uint(p2), 0x07060302u);
        pw32[q*32 + (((c0 + q)     & 7) << 2) + dwl] = w0;
        pw32[q*32 + (((c0 + q + 4) & 7) << 2) + dwl] = w1;
      }
    }

    // PV: V fragments straight from L2 (Vt row d, positions tk0..tk0+63)
    __builtin_amdgcn_s_setprio(1);
    #pragma unroll
    for (int ss = 0; ss < 2; ++ss) {
      short8 pf0 = *(const short8*)&pw[l16*64      + ((4*ss + quad + l16) & 7)*8];
      short8 pf1 = *(const short8*)&pw[(16+l16)*64 + ((4*ss + quad + l16) & 7)*8];
      #pragma unroll
      for (int nd = 0; nd < 4; ++nd) {
        short8 vf = *(const short8*)(vbase + (size_t)(nd*16) * T_ + tk0 + ss*32);
        o[0][nd] = MFMA16(pf0, vf, o[0][nd]);
        o[1][nd] = MFMA16(pf1, vf, o[1][nd]);
      }
    }
    __builtin_amdgcn_s_setprio(0);
  }

  // epilogue: reduce l across the 16-lane row, then O/l -> att[b,t,h*64+d]
  #pragma unroll
  for (int mt = 0; mt < 2; ++mt) {
    #pragma unroll
    for (int r = 0; r < 4; ++r) {
      float lsum = lrow[mt][r];
      lsum += __shfl_xor(lsum, 1);
      lsum += __shfl_xor(lsum, 2);
      lsum += __shfl_xor(lsum, 4);
      lsum += __shfl_xor(lsum, 8);
      const float inv = 1.0f / lsum;
      const int tt = qbase + mt*16 + quad*4 + r;
      #pragma unroll
      for (int nd = 0; nd < 4; ++nd)
        att[(size_t)(b*T_ + tt) * C_ + h*64 + nd*16 + l16] =
            __float2bfloat16(o[mt][nd][r] * inv);
    }
  }
}

extern "C" void kernel_launch(void* const* d_in, const int* in_sizes, int n_in,
                              void* d_out, int out_size, void* d_ws, size_t ws_size,
                              hipStream_t stream) {
  const float* x     = (const float*)d_in[0];
  const float* Wqkv  = (const float*)d_in[1];
  const float* Wproj = (const float*)d_in[2];
  const float* bproj = (const float*)d_in[3];
  float* out = (float*)d_out;

  char* ws = (char*)d_ws;
  bf16* xb     = (bf16*)(ws + 0);          // 8192x1024       16,777,216 B
  bf16* wqkvT  = (bf16*)(ws + 16777216);   // 3072x1024        6,291,456 B
  bf16* wprojT = (bf16*)(ws + 23068672);   // 1024x1024        2,097,152 B
  bf16* Qb     = (bf16*)(ws + 25165824);   // [B,H,T,HS]      16,777,216 B
  bf16* Kb     = (bf16*)(ws + 41943040);   // [B,H,T,HS]      16,777,216 B
  bf16* Vt     = (bf16*)(ws + 58720256);   // [B,H,HS,T] perm 16,777,216 B
  bf16* att    = (bf16*)(ws + 75497472);   // [B,T,C]         16,777,216 B

  k_prep<<<dim3(5120), 256, 0, stream>>>(x, xb, Wqkv, wqkvT, Wproj, wprojT);
  k_gemmqkv<<<dim3(256), 512, 0, stream>>>(xb, wqkvT, Qb, Kb, Vt);
  k_attn<<<dim3(1024), 256, 0, stream>>>(Qb, Kb, Vt, att);
  k_proj<8><<<dim3(512), 256, 0, stream>>>(
      att, wprojT, C_, C_, out, bproj);
}

// Round 12
// 215.615 us; speedup vs baseline: 1.4054x; 1.4054x over previous
//
#include <hip/hip_runtime.h>
#include <hip/hip_bf16.h>
#include <cstdint>
#include <cstddef>

using bf16 = __hip_bfloat16;
typedef __attribute__((ext_vector_type(8))) short short8;
typedef __attribute__((ext_vector_type(4))) float floatx4;

#define B_ 4
#define T_ 2048
#define C_ 1024
#define H_ 16
#define HS_ 64
#define BT_ (B_*T_)
#define N3C (3*C_)

#define MFMA16(a,b,c) __builtin_amdgcn_mfma_f32_16x16x32_bf16((a),(b),(c),0,0,0)

#if __has_builtin(__builtin_amdgcn_exp2f)
#define EXP2(x) __builtin_amdgcn_exp2f(x)
#else
#define EXP2(x) exp2f(x)
#endif

static __device__ __forceinline__ void gld16(const bf16* g, bf16* l) {
  __builtin_amdgcn_global_load_lds(
      (const __attribute__((address_space(1))) unsigned int*)g,
      (__attribute__((address_space(3))) unsigned int*)l, 16, 0, 0);
}

static __device__ __forceinline__ unsigned short f2bf_us(float x) {
  bf16 b = __float2bfloat16(x);
  return *(unsigned short*)&b;
}

// ---------------- fused prep: cast x + transpose-cast both weights ----------
__global__ __launch_bounds__(256)
void k_prep(const float* __restrict__ x, bf16* __restrict__ xb,
            const float* __restrict__ Wqkv, bf16* __restrict__ wqkvT,
            const float* __restrict__ Wproj, bf16* __restrict__ wprojT)
{
  const int bid = blockIdx.x, tid = threadIdx.x;
  __shared__ float tile[64][65];

  if (bid < 4096) {
    const int i = bid*256 + tid;
    const float4 v0 = ((const float4*)x)[2*i];
    const float4 v1 = ((const float4*)x)[2*i + 1];
    union { bf16 b[8]; uint4 u; } cvt;
    cvt.b[0] = __float2bfloat16(v0.x);
    cvt.b[1] = __float2bfloat16(v0.y);
    cvt.b[2] = __float2bfloat16(v0.z);
    cvt.b[3] = __float2bfloat16(v0.w);
    cvt.b[4] = __float2bfloat16(v1.x);
    cvt.b[5] = __float2bfloat16(v1.y);
    cvt.b[6] = __float2bfloat16(v1.z);
    cvt.b[7] = __float2bfloat16(v1.w);
    ((uint4*)xb)[i] = cvt.u;
    return;
  }

  const float* in; bf16* out; int N, n0, k0;
  if (bid < 4864) {
    const int j = bid - 4096;
    in = Wqkv; out = wqkvT; N = N3C;
    n0 = (j % 48) * 64; k0 = (j / 48) * 64;
  } else {
    const int j = bid - 4864;
    in = Wproj; out = wprojT; N = C_;
    n0 = (j % 16) * 64; k0 = (j / 16) * 64;
  }
  const int r = tid >> 6, c = tid & 63;
  #pragma unroll
  for (int j = 0; j < 16; ++j)
    tile[r + j*4][c] = in[(size_t)(k0 + r + j*4) * N + n0 + c];
  __syncthreads();
  #pragma unroll
  for (int j = 0; j < 16; ++j) {
    int rr = r + j*4;
    out[(size_t)(n0 + rr) * C_ + k0 + c] = __float2bfloat16(tile[c][rr]);
  }
}

// ---------------- QKV GEMM: 256x384, BK=32, 3-buf, 1-barrier/tile -----------
// R16 structure (proven): grid 256 = 1 block/CU tail-free; BN=384 as {Q,K,V}
// 128-col groups; 8 waves 2Mx4N acc[8][6]; verified 0-conflict swizzle;
// one counted vmcnt(5) + one barrier per K-tile, free-scheduling window.
__global__ __launch_bounds__(512, 1)
void k_gemmqkv(const bf16* __restrict__ A, const bf16* __restrict__ Bt,
               bf16* __restrict__ Qb, bf16* __restrict__ Kb, bf16* __restrict__ Vt)
{
  __shared__ __align__(16) char smem[122880];
  bf16* const sA = (bf16*)smem;                 // [3][8192]  256 rows x 32
  bf16* const sB = (bf16*)(smem + 49152);       // [3][12288] 384 rows x 32

  const int tid  = threadIdx.x;
  const int lane = tid & 63, wave = tid >> 6;
  const int quad = lane >> 4, l16 = lane & 15;
  const int wm = wave >> 2, wn = wave & 3;      // 2M x 4N

  const int g = blockIdx.x;                     // 256 blocks
  const int xcd = g & 7;
  const int local = g >> 3;                     // 0..31
  const int nb = local & 7;
  const int mb = (local >> 3) * 8 + xcd;        // 0..31
  const int m0 = mb * 256;
  const int n0q = nb * 128;

  const int ra = tid >> 2;
  const int gc = (tid & 3) ^ ((ra >> 1) & 3);
  const bf16* aptr = A  + (size_t)(m0 + ra) * C_ + gc*8;
  const bf16* bp0  = Bt + (size_t)(n0q + ra) * C_ + gc*8;          // Q group
  const bf16* bp1  = Bt + (size_t)(1024 + n0q + ra) * C_ + gc*8;   // K group
  const bf16* bp2  = Bt + (size_t)(2048 + n0q + ra) * C_ + gc*8;   // V group

  floatx4 acc[8][6] = {};
  const int swz = (l16 >> 1) & 3;
  const int aoff = (wm*128 + l16)*32 + (quad ^ swz)*8;
  const int boff = (wn*96  + l16)*32 + (quad ^ swz)*8;

#define STAGE_A(t,s) { bf16* d = sA + (s)*8192;                     \
    gld16(aptr + (t)*32,                  d + tid*8);               \
    gld16(aptr + (size_t)128*C_ + (t)*32, d + 4096 + tid*8); }
#define STAGE_B(t,s) { bf16* d = sB + (s)*12288;                    \
    gld16(bp0 + (t)*32, d + tid*8);                                 \
    gld16(bp1 + (t)*32, d + 4096 + tid*8);                         \
    gld16(bp2 + (t)*32, d + 8192 + tid*8); }

  // prologue: tiles 0,1 staged (10 loads in flight; 5 per tile per wave)
  STAGE_A(0,0); STAGE_B(0,0);
  STAGE_A(1,1); STAGE_B(1,1);

  int cs = 0;                                   // i % 3
  #pragma unroll 1
  for (int i = 0; i < 32; ++i) {
    const int s2 = (cs >= 1) ? cs - 1 : 2;      // (i+2) % 3
    if (i < 31) asm volatile("s_waitcnt vmcnt(5)" ::: "memory");  // tile i done
    else        asm volatile("s_waitcnt vmcnt(0)" ::: "memory");
    __builtin_amdgcn_sched_barrier(0);          // tile boundary: no reg-op motion
    asm volatile("s_barrier" ::: "memory");
    if (i < 30) { STAGE_A(i+2, s2); STAGE_B(i+2, s2); }
    const bf16* sa = sA + cs*8192;
    const bf16* sb = sB + cs*12288;
    short8 bq[6], af[4];
    #pragma unroll
    for (int j = 0; j < 6; ++j)    bq[j]  = *(const short8*)&sb[boff + j*512];
    #pragma unroll
    for (int ii = 0; ii < 4; ++ii) af[ii] = *(const short8*)&sa[aoff + ii*512];
    __builtin_amdgcn_s_setprio(1);
    #pragma unroll
    for (int ii = 0; ii < 4; ++ii)
      #pragma unroll
      for (int j = 0; j < 6; ++j)
        acc[ii][j] = MFMA16(af[ii], bq[j], acc[ii][j]);
    __builtin_amdgcn_s_setprio(0);
    #pragma unroll
    for (int ii = 0; ii < 4; ++ii) af[ii] = *(const short8*)&sa[aoff + (4+ii)*512];
    __builtin_amdgcn_s_setprio(1);
    #pragma unroll
    for (int ii = 0; ii < 4; ++ii)
      #pragma unroll
      for (int j = 0; j < 6; ++j)
        acc[4+ii][j] = MFMA16(af[ii], bq[j], acc[4+ii][j]);
    __builtin_amdgcn_s_setprio(0);
    cs = (cs == 2) ? 0 : cs + 1;
  }
#undef STAGE_A
#undef STAGE_B

  // ---- Q/K scatter (local cols 0-255) ----
  #pragma unroll
  for (int ii = 0; ii < 8; ++ii) {
    const int rowb = m0 + wm*128 + ii*16 + quad*4;
    #pragma unroll
    for (int j = 0; j < 6; ++j) {
      const int L = wn*96 + j*16 + l16;          // 16-aligned span: uniform side
      if (L < 256) {
        const int gcol = (L < 128) ? (n0q + L) : (1024 + n0q + L - 128);
        const int h = (gcol >> 6) & 15, d = gcol & 63;
        #pragma unroll
        for (int r = 0; r < 4; ++r) {
          const int rr = rowb + r;
          const int b = rr >> 11, t = rr & 2047;
          const size_t addr = (((size_t)(b*H_ + h) * T_ + t) << 6) + d;
          if (L < 128) Qb[addr] = __float2bfloat16(acc[ii][j][r] * 0.18033688f);
          else         Kb[addr] = __float2bfloat16(acc[ii][j][r]);
        }
      }
    }
  }

  // ---- V (local cols 256-383): LDS transpose -> key-permuted Vt ----
  __syncthreads();                               // all waves done with sA/sB
  unsigned short* epi = (unsigned short*)smem;   // [128 cc][258 tl-pad]
  #pragma unroll
  for (int ii = 0; ii < 8; ++ii) {
    const int tl = wm*128 + ii*16 + quad*4;
    #pragma unroll
    for (int j = 0; j < 6; ++j) {
      const int L = wn*96 + j*16 + l16;
      if (L >= 256) {
        const int ccl = L - 256;                 // 0..127
        #pragma unroll
        for (int r = 0; r < 4; ++r)
          epi[ccl*258 + tl + r] = f2bf_us(acc[ii][j][r]);
      }
    }
  }
  __syncthreads();
  const int b  = m0 >> 11;
  const int t0 = m0 & 2047;
  #pragma unroll
  for (int it = 0; it < 32; ++it) {
    const int id = it*512 + tid;                 // 16384 dword-pairs
    const int tp = id & 31;
    const int rest = id >> 5;                    // 0..511
    const int tl64 = (rest & 3) * 64;            // 64-token group of 256 rows
    const int ccl = rest >> 2;                   // 0..127
    const int k0p = tp + (tp & 16);              // keys (k0p,k0p+16)->(2tp,2tp+1)
    const unsigned lo = epi[ccl*258 + tl64 + k0p];
    const unsigned hi = epi[ccl*258 + tl64 + k0p + 16];
    const int h = nb*2 + (ccl >> 6), d = ccl & 63;
    unsigned* row = (unsigned*)(Vt + ((size_t)(b*H_ + h) * HS_ + d) * T_);
    row[(t0 >> 1) + tl64/2 + tp] = lo | (hi << 16);
  }
}

// ---------------- proj GEMM: 128x128, BK=32, 4-deep counted-vmcnt -----------
template<int NB>
__global__ __launch_bounds__(256, 2)
void k_proj(const bf16* __restrict__ A, const bf16* __restrict__ Bt,
            int N, int K, float* __restrict__ Out, const float* __restrict__ bias)
{
  __shared__ __align__(16) char smem[65536];
  bf16* const sA = (bf16*)smem;               // [4][4096]  128 rows x 32
  bf16* const sB = (bf16*)(smem + 32768);     // [4][4096]

  const int tid  = threadIdx.x;
  const int lane = tid & 63, wave = tid >> 6;
  const int quad = lane >> 4, l16 = lane & 15;
  const int wm = wave >> 1, wn = wave & 1;

  const int g = blockIdx.x;
  const int xcd = g & 7;
  const int local = g >> 3;
  const int nb = local % NB;
  const int mb = (local / NB) * 8 + xcd;
  const int m0 = mb * 128, n0 = nb * 128;

  const int ra = tid >> 2;
  const int gc = (tid & 3) ^ ((ra >> 1) & 3);
  const bf16* aptr = A  + (size_t)(m0 + ra) * K + gc*8;
  const bf16* bptr = Bt + (size_t)(n0 + ra) * K + gc*8;
  const size_t rj = (size_t)64 * K;

  const int KT = K >> 5;                      // 32 K-tiles
  floatx4 acc[4][4] = {};
  const int swz = (l16 >> 1) & 3;
  const int aoff = (wm*64 + l16)*32 + (quad ^ swz)*8;
  const int boff = (wn*64 + l16)*32 + (quad ^ swz)*8;

  #pragma unroll
  for (int t = 0; t < 3; ++t) {
    bf16* sa = sA + t*4096; bf16* sb = sB + t*4096;
    gld16(aptr + t*32,      sa + tid*8);
    gld16(aptr + rj + t*32, sa + 2048 + tid*8);
    gld16(bptr + t*32,      sb + tid*8);
    gld16(bptr + rj + t*32, sb + 2048 + tid*8);
  }

  #pragma unroll 1
  for (int i = 0; i < KT; ++i) {
    if (i < KT-2)       asm volatile("s_waitcnt vmcnt(8)" ::: "memory");
    else if (i == KT-2) asm volatile("s_waitcnt vmcnt(4)" ::: "memory");
    else                asm volatile("s_waitcnt vmcnt(0)" ::: "memory");
    asm volatile("s_barrier" ::: "memory");
    if (i < KT-3) {
      const int t = i + 3;
      bf16* sa = sA + (t & 3)*4096; bf16* sb = sB + (t & 3)*4096;
      gld16(aptr + t*32,      sa + tid*8);
      gld16(aptr + rj + t*32, sa + 2048 + tid*8);
      gld16(bptr + t*32,      sb + tid*8);
      gld16(bptr + rj + t*32, sb + 2048 + tid*8);
    }
    const bf16* sa = sA + (i & 3)*4096;
    const bf16* sb = sB + (i & 3)*4096;
    short8 af[4], bfm[4];
    #pragma unroll
    for (int ii = 0; ii < 4; ++ii) af[ii]  = *(const short8*)&sa[aoff + ii*512];
    #pragma unroll
    for (int j = 0; j < 4; ++j)    bfm[j]  = *(const short8*)&sb[boff + j*512];
    __builtin_amdgcn_s_setprio(1);
    #pragma unroll
    for (int ii = 0; ii < 4; ++ii)
      #pragma unroll
      for (int j = 0; j < 4; ++j)
        acc[ii][j] = MFMA16(af[ii], bfm[j], acc[ii][j]);
    __builtin_amdgcn_s_setprio(0);
  }

  #pragma unroll
  for (int i = 0; i < 4; ++i) {
    const int rowb = m0 + wm*64 + i*16 + quad*4;
    #pragma unroll
    for (int j = 0; j < 4; ++j) {
      const int col = n0 + wn*64 + j*16 + l16;
      #pragma unroll
      for (int r = 0; r < 4; ++r)
        Out[(size_t)(rowb + r) * N + col] = acc[i][j][r] + bias[col];
    }
  }
}

// ---------------- flash attention (causal) ----------------------------------
// R21: restored R10/R7 attn (best reproduced config). Refuted alternatives:
// 8-wave 256-row tiles (74-93us, both VGPR variants), L2-direct K/V reads
// (143us: lost cooperative reuse + load-latency on MFMA critical path).
// Shared LDS staging with 4-wave blocks at 3 blocks/CU is the empirical
// optimum of all tested structures (~55us).
__global__ __launch_bounds__(256, 3)
void k_attn(const bf16* __restrict__ Q, const bf16* __restrict__ K,
            const bf16* __restrict__ Vt, bf16* __restrict__ att)
{
  __shared__ bf16 kbuf[2][64*64];   // [buf][key][dc^key&7]
  __shared__ bf16 vbuf[2][64*64];   // [buf][d][pc^d&7]  (positions, permuted)
  __shared__ bf16 pbuf[4][32*64];   // per-wave [q][(pc+q)&7 rotation]

  const int tid  = threadIdx.x;
  const int lane = tid & 63, wave = tid >> 6;
  const int quad = lane >> 4, l16 = lane & 15;
  const int x7 = l16 & 7;

  const int g  = blockIdx.x;              // 1024 blocks
  const int bh = (g & 7) * 8 + ((g >> 3) & 7);  // 16 blocks of a bh share XCD g&7
  const int qt = 15 - (g >> 6);           // q-tile index; heavy (qt=15) first
  const int b = bh >> 4, h = bh & 15;

  const bf16* Qp = Q  + (size_t)bh * T_ * HS_;
  const bf16* Kp = K  + (size_t)bh * T_ * HS_;
  const bf16* Vp = Vt + (size_t)bh * HS_ * T_;

  const int qbase = qt*128 + wave*32;
  const int ntk = 2*qt + 2;               // key tiles to process

  short8 qf[2][2];
  #pragma unroll
  for (int mt = 0; mt < 2; ++mt)
    #pragma unroll
    for (int ss = 0; ss < 2; ++ss)
      qf[mt][ss] = *(const short8*)(Qp + (size_t)(qbase + mt*16 + l16) * HS_ + ss*32 + quad*8);

  floatx4 o[2][4] = {};
  float lrow[2][4] = {};

  const bf16* kg[2]; const bf16* vg[2];
  int ldsoff[2];
  #pragma unroll
  for (int it = 0; it < 2; ++it) {
    const int c = it*256 + tid;
    const int row = c >> 3;
    const int col = (c & 7) ^ (row & 7);
    kg[it] = Kp + (size_t)row * HS_ + col*8;
    vg[it] = Vp + (size_t)row * T_ + col*8;
    ldsoff[it] = c*8;
  }

  bf16* pw = pbuf[wave];
  unsigned int* pw32 = (unsigned int*)pw;
  const int c0 = l16 >> 2;
  const int dwl = l16 & 3;

  for (int i = 0; i <= ntk; ++i) {
    __syncthreads();
    if (i < ntk) {
      const int stk0 = i * 64;
      bf16* kb = kbuf[i & 1];
      bf16* vb = vbuf[i & 1];
      #pragma unroll
      for (int it = 0; it < 2; ++it) {
        gld16(kg[it] + (size_t)stk0 * HS_, kb + ldsoff[it]);
        gld16(vg[it] + stk0,               vb + ldsoff[it]);
      }
    }
    if (i == 0) continue;
    const int tk  = i - 1;
    const int tk0 = tk * 64;
    if (tk0 > qbase + 31) continue;
    const bf16* kb = kbuf[tk & 1];
    const bf16* vb = vbuf[tk & 1];

    floatx4 s[2][4] = {};
    __builtin_amdgcn_s_setprio(1);
    #pragma unroll
    for (int nt = 0; nt < 4; ++nt) {
      const int key = nt*16 + l16;
      #pragma unroll
      for (int ss = 0; ss < 2; ++ss) {
        short8 kf = *(const short8*)&kb[(key*8 + ((ss*4+quad) ^ x7))*8];
        s[0][nt] = MFMA16(qf[0][ss], kf, s[0][nt]);
        s[1][nt] = MFMA16(qf[1][ss], kf, s[1][nt]);
      }
    }
    __builtin_amdgcn_s_setprio(0);

    if (tk0 + 63 > qbase) {
      #pragma unroll
      for (int mt = 0; mt < 2; ++mt)
        #pragma unroll
        for (int nt = 0; nt < 4; ++nt) {
          const int key = tk0 + nt*16 + l16;
          #pragma unroll
          for (int r = 0; r < 4; ++r) {
            const int qr = qbase + mt*16 + quad*4 + r;
            if (key > qr) s[mt][nt][r] = -1e30f;
          }
        }
    }

    #pragma unroll
    for (int mt = 0; mt < 2; ++mt) {
      #pragma unroll
      for (int r = 0; r < 4; ++r) {
        const float p0 = EXP2(s[mt][0][r]), p1 = EXP2(s[mt][1][r]);
        const float p2 = EXP2(s[mt][2][r]), p3 = EXP2(s[mt][3][r]);
        lrow[mt][r] += (p0 + p1) + (p2 + p3);
        const int q = mt*16 + quad*4 + r;
        const unsigned w0 = __builtin_amdgcn_perm(__float_as_uint(p1), __float_as_uint(p0), 0x07060302u);
        const unsigned w1 = __builtin_amdgcn_perm(__float_as_uint(p3), __float_as_uint(p2), 0x07060302u);
        pw32[q*32 + (((c0 + q)     & 7) << 2) + dwl] = w0;
        pw32[q*32 + (((c0 + q + 4) & 7) << 2) + dwl] = w1;
      }
    }

    __builtin_amdgcn_s_setprio(1);
    #pragma unroll
    for (int ss = 0; ss < 2; ++ss) {
      short8 pf0 = *(const short8*)&pw[l16*64      + ((4*ss + quad + l16) & 7)*8];
      short8 pf1 = *(const short8*)&pw[(16+l16)*64 + ((4*ss + quad + l16) & 7)*8];
      #pragma unroll
      for (int nd = 0; nd < 4; ++nd) {
        const int d = nd*16 + l16;
        short8 vf = *(const short8*)&vb[(d*8 + ((ss*4+quad) ^ x7))*8];
        o[0][nd] = MFMA16(pf0, vf, o[0][nd]);
        o[1][nd] = MFMA16(pf1, vf, o[1][nd]);
      }
    }
    __builtin_amdgcn_s_setprio(0);
  }

  #pragma unroll
  for (int mt = 0; mt < 2; ++mt) {
    #pragma unroll
    for (int r = 0; r < 4; ++r) {
      float lsum = lrow[mt][r];
      lsum += __shfl_xor(lsum, 1);
      lsum += __shfl_xor(lsum, 2);
      lsum += __shfl_xor(lsum, 4);
      lsum += __shfl_xor(lsum, 8);
      const float inv = 1.0f / lsum;
      const int tt = qbase + mt*16 + quad*4 + r;
      #pragma unroll
      for (int nd = 0; nd < 4; ++nd)
        att[(size_t)(b*T_ + tt) * C_ + h*64 + nd*16 + l16] =
            __float2bfloat16(o[mt][nd][r] * inv);
    }
  }
}

extern "C" void kernel_launch(void* const* d_in, const int* in_sizes, int n_in,
                              void* d_out, int out_size, void* d_ws, size_t ws_size,
                              hipStream_t stream) {
  const float* x     = (const float*)d_in[0];
  const float* Wqkv  = (const float*)d_in[1];
  const float* Wproj = (const float*)d_in[2];
  const float* bproj = (const float*)d_in[3];
  float* out = (float*)d_out;

  char* ws = (char*)d_ws;
  bf16* xb     = (bf16*)(ws + 0);          // 8192x1024       16,777,216 B
  bf16* wqkvT  = (bf16*)(ws + 16777216);   // 3072x1024        6,291,456 B
  bf16* wprojT = (bf16*)(ws + 23068672);   // 1024x1024        2,097,152 B
  bf16* Qb     = (bf16*)(ws + 25165824);   // [B,H,T,HS]      16,777,216 B
  bf16* Kb     = (bf16*)(ws + 41943040);   // [B,H,T,HS]      16,777,216 B
  bf16* Vt     = (bf16*)(ws + 58720256);   // [B,H,HS,T] perm 16,777,216 B
  bf16* att    = (bf16*)(ws + 75497472);   // [B,T,C]         16,777,216 B

  k_prep<<<dim3(5120), 256, 0, stream>>>(x, xb, Wqkv, wqkvT, Wproj, wprojT);
  k_gemmqkv<<<dim3(256), 512, 0, stream>>>(xb, wqkvT, Qb, Kb, Vt);
  k_attn<<<dim3(1024), 256, 0, stream>>>(Qb, Kb, Vt, att);
  k_proj<8><<<dim3(512), 256, 0, stream>>>(
      att, wprojT, C_, C_, out, bproj);
}